// Round 10
// baseline (260.127 us; speedup 1.0000x reference)
//
#include <hip/hip_runtime.h>
#include <hip/hip_bf16.h>
#include <math.h>

#define EPSV 1e-8f

typedef float floatx4 __attribute__((ext_vector_type(4)));

// ---------- DPP helpers (VALU-only cross-lane, no LDS pipe) ----------
template <int CTRL, bool ZERO>
__device__ __forceinline__ float fdpp(float v) {
  return __int_as_float(__builtin_amdgcn_update_dpp(
      ZERO ? 0 : __float_as_int(v), __float_as_int(v), CTRL, 0xF, 0xF, ZERO));
}
// quad_perm xor1=0xB1, xor2=0x4E; row_half_mirror(xor7)=0x141
// row_shr n=0x110+n; bcast15=0x142; bcast31=0x143
__device__ __forceinline__ float rdl63(float v) {
  return __int_as_float(__builtin_amdgcn_readlane(__float_as_int(v), 63));
}
// 8-lane-group reductions (XOR-butterfly masks {1,2,7} span 0..7)
__device__ __forceinline__ float gsum8(float v) {
  v += fdpp<0xB1, true>(v);
  v += fdpp<0x4E, true>(v);
  v += fdpp<0x141, true>(v);
  return v;
}
__device__ __forceinline__ float gmax8(float v) {
  v = fmaxf(v, fdpp<0xB1, false>(v));
  v = fmaxf(v, fdpp<0x4E, false>(v));
  v = fmaxf(v, fdpp<0x141, false>(v));
  return v;
}
__device__ __forceinline__ float wsum_dpp(float v) {
  v += fdpp<0x111, true>(v);
  v += fdpp<0x112, true>(v);
  v += fdpp<0x114, true>(v);
  v += fdpp<0x118, true>(v);
  v += fdpp<0x142, true>(v);
  v += fdpp<0x143, true>(v);
  return rdl63(v);
}
__device__ __forceinline__ float wmax_dpp(float v) {
  v = fmaxf(v, fdpp<0x111, false>(v));
  v = fmaxf(v, fdpp<0x112, false>(v));
  v = fmaxf(v, fdpp<0x114, false>(v));
  v = fmaxf(v, fdpp<0x118, false>(v));
  v = fmaxf(v, fdpp<0x142, false>(v));
  v = fmaxf(v, fdpp<0x143, false>(v));
  return rdl63(v);
}
__device__ __forceinline__ float wmin_dpp(float v) {
  v = fminf(v, fdpp<0x111, false>(v));
  v = fminf(v, fdpp<0x112, false>(v));
  v = fminf(v, fdpp<0x114, false>(v));
  v = fminf(v, fdpp<0x118, false>(v));
  v = fminf(v, fdpp<0x142, false>(v));
  v = fminf(v, fdpp<0x143, false>(v));
  return rdl63(v);
}

__device__ __forceinline__ float wsum64(float v) {  // stages 2/3
#pragma unroll
  for (int m = 1; m <= 32; m <<= 1) v += __shfl_xor(v, m);
  return v;
}

// Non-temporal float4 load (native clang vector type — builtin requires it).
__device__ __forceinline__ floatx4 ntload4(const float* p) {
  return __builtin_nontemporal_load((const floatx4*)p);
}

// One workgroup per (b, s, n): 4096 blocks x 512 threads (8 waves).
// 8 lanes per (l) row, each lane owns 8 elements. 2-h batching: 4 nt-loads
// issued back-to-back per iteration (4 KB/wave outstanding). Low VGPR ->
// 8 waves/SIMD (32 waves/CU).
__global__ __launch_bounds__(512, 8) void stage1_kernel(
    const float* __restrict__ sat, float* __restrict__ node,
    float* __restrict__ edge, float* __restrict__ score) {
  const int bid = blockIdx.x;
  const int n = bid & 63;
  const int bs = bid >> 6;
  const int tbase = bs * 64;

  __shared__ float Ps[64][64];
  __shared__ float ent_s[64];
  __shared__ float diff_s[64];
  __shared__ float psum_s[8][64];
  __shared__ float dsq_s[8][64];

  const int tid = threadIdx.x;
  const int wave = tid >> 6;   // 0..7
  const int lane = tid & 63;
  const int rsub = lane >> 3;  // row-in-wave 0..7
  const int sl = lane & 7;     // sub-lane in row
  const int l = wave * 8 + rsub;

  // ---- phase 1: softmax over j (64), mean over h (8) -> Ps[l][j] ----
  // lane holds elements j = sl*4..sl*4+3 and sl*4+32..sl*4+35
  const float* rowb =
      sat + (size_t)(tbase + l) * 32768 + n * 64 + sl * 4;

  float acc[8];
#pragma unroll
  for (int c = 0; c < 8; ++c) acc[c] = 0.f;

#pragma unroll
  for (int hp = 0; hp < 4; ++hp) {
    const float* pa = rowb + (2 * hp) * 4096;
    const float* pb = pa + 4096;
    // 4 independent nt loads issued back-to-back (4 KB in flight per wave)
    floatx4 a0 = ntload4(pa);
    floatx4 a1 = ntload4(pa + 32);
    floatx4 b0 = ntload4(pb);
    floatx4 b1 = ntload4(pb + 32);

    {
      float m = fmaxf(fmaxf(fmaxf(a0.x, a0.y), fmaxf(a0.z, a0.w)),
                      fmaxf(fmaxf(a1.x, a1.y), fmaxf(a1.z, a1.w)));
      m = gmax8(m);
      float e0 = __expf(a0.x - m), e1 = __expf(a0.y - m);
      float e2 = __expf(a0.z - m), e3 = __expf(a0.w - m);
      float e4 = __expf(a1.x - m), e5 = __expf(a1.y - m);
      float e6 = __expf(a1.z - m), e7 = __expf(a1.w - m);
      float s = gsum8(((e0 + e1) + (e2 + e3)) + ((e4 + e5) + (e6 + e7)));
      float inv = 1.0f / s;
      acc[0] += e0 * inv; acc[1] += e1 * inv;
      acc[2] += e2 * inv; acc[3] += e3 * inv;
      acc[4] += e4 * inv; acc[5] += e5 * inv;
      acc[6] += e6 * inv; acc[7] += e7 * inv;
    }
    {
      float m = fmaxf(fmaxf(fmaxf(b0.x, b0.y), fmaxf(b0.z, b0.w)),
                      fmaxf(fmaxf(b1.x, b1.y), fmaxf(b1.z, b1.w)));
      m = gmax8(m);
      float e0 = __expf(b0.x - m), e1 = __expf(b0.y - m);
      float e2 = __expf(b0.z - m), e3 = __expf(b0.w - m);
      float e4 = __expf(b1.x - m), e5 = __expf(b1.y - m);
      float e6 = __expf(b1.z - m), e7 = __expf(b1.w - m);
      float s = gsum8(((e0 + e1) + (e2 + e3)) + ((e4 + e5) + (e6 + e7)));
      float inv = 1.0f / s;
      acc[0] += e0 * inv; acc[1] += e1 * inv;
      acc[2] += e2 * inv; acc[3] += e3 * inv;
      acc[4] += e4 * inv; acc[5] += e5 * inv;
      acc[6] += e6 * inv; acc[7] += e7 * inv;
    }
  }

  // entropy in-register (head-avg applied first)
  float ent = 0.f;
#pragma unroll
  for (int c = 0; c < 8; ++c) {
    acc[c] *= 0.125f;
    float pc = fmaxf(acc[c], EPSV);
    ent += pc * __logf(pc);
  }
  ent = gsum8(ent);
  if (sl == 0) ent_s[l] = -ent;

  *(float4*)&Ps[l][sl * 4] = *(float4*)&acc[0];
  *(float4*)&Ps[l][sl * 4 + 32] = *(float4*)&acc[4];
  __syncthreads();

  // ---- phase 2a: per-j partials over this wave's 8 rows + TV row sums ----
  {
    const int base = wave * 8;
    float psum = 0.f, dsq = 0.f;
    float p = Ps[base][lane];
#pragma unroll 1
    for (int i = 0; i < 8; ++i) {
      const int ll = base + i;
      psum += p;
      if (ll < 63) {
        float pn = Ps[ll + 1][lane];
        float d = pn - p;
        dsq += d * d;
        float ad = fabsf(d);
        ad += fdpp<0x111, true>(ad);
        ad += fdpp<0x112, true>(ad);
        ad += fdpp<0x114, true>(ad);
        ad += fdpp<0x118, true>(ad);
        ad += fdpp<0x142, true>(ad);
        ad += fdpp<0x143, true>(ad);
        if (lane == 63) diff_s[ll] = ad;
        p = pn;
      }
    }
    psum_s[wave][lane] = psum;
    dsq_s[wave][lane] = dsq;
  }
  __syncthreads();

  // ---- phase 2c: edge features (wave 1) ----
  if (wave == 1) {
    const int j = lane;
    float tot = 0.f, dsq = 0.f;
#pragma unroll
    for (int w = 0; w < 8; ++w) {
      tot += psum_s[w][j];
      dsq += dsq_s[w][j];
    }
    float pem = tot * (1.0f / 64.0f);
    float dmean = (Ps[63][j] - Ps[0][j]) * (1.0f / 63.0f);
    float dvar = (dsq - 63.0f * dmean * dmean) * (1.0f / 62.0f);
    float dstd = sqrtf(fmaxf(dvar, 0.f));
    size_t eo = (size_t)bs * 4096 + (size_t)n * 64 + j;
    float4 ef = make_float4(pem, dstd, fmaxf(dmean, 0.f), fmaxf(-dmean, 0.f));
    *(float4*)(edge + eo * 4) = ef;
    score[eo] = (j == n) ? 0.f : fabsf(dmean);
  }

  // ---- phase 2d: node features (wave 0), two-pass variance, DPP ----
  if (wave == 0) {
    float e = ent_s[lane];
    float dg = Ps[lane][n];
    bool dv = lane < 63;
    float df = dv ? diff_s[lane] : 0.f;

    float emean = wsum_dpp(e) * (1.0f / 64.0f);
    float emax = wmax_dpp(e);
    float emin = wmin_dpp(e);
    float dgmean = wsum_dpp(dg) * (1.0f / 64.0f);
    float dfmean = wsum_dpp(df) * (1.0f / 63.0f);
    float dfmax = wmax_dpp(dv ? df : -INFINITY);

    float ed = e - emean;
    float evar = wsum_dpp(ed * ed) * (1.0f / 63.0f);
    float dgd = dg - dgmean;
    float dgvar = wsum_dpp(dgd * dgd) * (1.0f / 63.0f);
    float dfd = dv ? (df - dfmean) : 0.f;
    float dfvar = wsum_dpp(dfd * dfd) * (1.0f / 62.0f);

    if (lane == 0) {
      float* no = node + ((size_t)bs * 64 + n) * 9;
      no[0] = emean;
      no[1] = sqrtf(fmaxf(evar, 0.f));
      no[2] = emax - emin;
      no[3] = (ent_s[63] - ent_s[0]) * (1.0f / 63.0f);
      no[4] = dfmean;
      no[5] = sqrtf(fmaxf(dfvar, 0.f));
      no[6] = dfmax;
      no[7] = dgmean;
      no[8] = sqrtf(fmaxf(dgvar, 0.f));
    }
  }
}

// One workgroup per (b, s): top-16 extraction + feat assembly.
__global__ __launch_bounds__(256) void stage2_kernel(
    const float* __restrict__ node, const float* __restrict__ edge,
    const float* __restrict__ score, float* __restrict__ feat) {
  const int bsid = blockIdx.x;  // b*4+s
  const int b = bsid >> 2, s = bsid & 3;
  __shared__ float sc[4096];
  __shared__ int widx[16];
  __shared__ float rv[4];
  __shared__ int ri[4];
  const int tid = threadIdx.x;
  const int wave = tid >> 6, lane = tid & 63;

  const float* scg = score + (size_t)bsid * 4096;
  for (int i = tid; i < 4096; i += 256) sc[i] = scg[i];
  __syncthreads();

  for (int k = 0; k < 16; ++k) {
    float bv = -1.f;
    int bi = 1 << 30;
    for (int i = tid; i < 4096; i += 256) {
      float v = sc[i];
      if (v > bv) { bv = v; bi = i; }
    }
#pragma unroll
    for (int mk = 1; mk <= 32; mk <<= 1) {
      float ov = __shfl_xor(bv, mk);
      int oi = __shfl_xor(bi, mk);
      if (ov > bv || (ov == bv && oi < bi)) { bv = ov; bi = oi; }
    }
    if (lane == 0) { rv[wave] = bv; ri[wave] = bi; }
    __syncthreads();
    if (tid == 0) {
      float fv = rv[0]; int fi = ri[0];
#pragma unroll
      for (int w = 1; w < 4; ++w)
        if (rv[w] > fv || (rv[w] == fv && ri[w] < fi)) { fv = rv[w]; fi = ri[w]; }
      widx[k] = fi;
      sc[fi] = -1.f;
    }
    __syncthreads();
  }

  float* fout = feat + (size_t)b * 2560 + s * 640;
  const float* nodeg = node + (size_t)bsid * 576;
  for (int i = tid; i < 576; i += 256) fout[i] = nodeg[i];
  if (tid < 16) {
    int idx = widx[tid];
    float4 ef = *(const float4*)(edge + ((size_t)bsid * 4096 + idx) * 4);
    *(float4*)(fout + 576 + tid * 4) = ef;
  }
}

// One workgroup per b: LayerNorm + MLP.
__global__ __launch_bounds__(256) void stage3_kernel(
    const float* __restrict__ feat, const float* __restrict__ gamma,
    const float* __restrict__ beta, const float* __restrict__ W1,
    const float* __restrict__ b1, const float* __restrict__ W2,
    const float* __restrict__ b2, float* __restrict__ out) {
  const int b = blockIdx.x;
  __shared__ float hf[2560];
  __shared__ float rs[4], rq[4];
  __shared__ float part[2][128];
  __shared__ float h1[128];
  __shared__ float part2[4][64];
  const int tid = threadIdx.x;
  const int wave = tid >> 6, lane = tid & 63;

  const float* f = feat + (size_t)b * 2560;
  float lsum = 0.f, lsq = 0.f;
  for (int i = tid; i < 2560; i += 256) {
    float v = f[i];
    hf[i] = v;
    lsum += v;
    lsq += v * v;
  }
  lsum = wsum64(lsum);
  lsq = wsum64(lsq);
  if (lane == 0) { rs[wave] = lsum; rq[wave] = lsq; }
  __syncthreads();
  float tsum = rs[0] + rs[1] + rs[2] + rs[3];
  float tsq = rq[0] + rq[1] + rq[2] + rq[3];
  float mean = tsum * (1.0f / 2560.0f);
  float var = tsq * (1.0f / 2560.0f) - mean * mean;
  float inv = rsqrtf(var + 1e-5f);
  for (int i = tid; i < 2560; i += 256)
    hf[i] = (hf[i] - mean) * inv * gamma[i] + beta[i];
  __syncthreads();

  {
    const int o = tid & 127, half = tid >> 7;
    float acc = 0.f;
    const int i0 = half * 1280;
    for (int i = i0; i < i0 + 1280; ++i) acc += hf[i] * W1[(size_t)i * 128 + o];
    part[half][o] = acc;
  }
  __syncthreads();
  if (tid < 128) h1[tid] = fmaxf(part[0][tid] + part[1][tid] + b1[tid], 0.f);
  __syncthreads();
  {
    const int o = tid & 63, pp = tid >> 6;
    float acc = 0.f;
    const int i0 = pp * 32;
    for (int i = i0; i < i0 + 32; ++i) acc += h1[i] * W2[i * 64 + o];
    part2[pp][o] = acc;
  }
  __syncthreads();
  if (tid < 64)
    out[(size_t)b * 64 + tid] =
        fmaxf(part2[0][tid] + part2[1][tid] + part2[2][tid] + part2[3][tid] + b2[tid], 0.f);
}

extern "C" void kernel_launch(void* const* d_in, const int* in_sizes, int n_in,
                              void* d_out, int out_size, void* d_ws, size_t ws_size,
                              hipStream_t stream) {
  const float* sat = (const float*)d_in[0];
  const float* gamma = (const float*)d_in[1];
  const float* beta = (const float*)d_in[2];
  const float* W1 = (const float*)d_in[3];
  const float* b1 = (const float*)d_in[4];
  const float* W2 = (const float*)d_in[5];
  const float* b2 = (const float*)d_in[6];
  float* out = (float*)d_out;

  float* ws = (float*)d_ws;
  float* edge = ws;                          // 16*4*4096*4 floats
  float* score = edge + 16 * 4 * 4096 * 4;   // 262144 floats
  float* node = score + 16 * 4 * 4096;       // 36864 floats
  float* feat = node + 16 * 4 * 64 * 9;      // 40960 floats

  stage1_kernel<<<4096, 512, 0, stream>>>(sat, node, edge, score);
  stage2_kernel<<<64, 256, 0, stream>>>(node, edge, score, feat);
  stage3_kernel<<<16, 256, 0, stream>>>(feat, gamma, beta, W1, b1, W2, b2, out);
}

// Round 11
// 202.720 us; speedup vs baseline: 1.2832x; 1.2832x over previous
//
#include <hip/hip_runtime.h>
#include <hip/hip_bf16.h>
#include <math.h>

#define EPSV 1e-8f

typedef float floatx4 __attribute__((ext_vector_type(4)));

// ---------- DPP helpers (VALU-only cross-lane, no LDS pipe) ----------
template <int CTRL, bool ZERO>
__device__ __forceinline__ float fdpp(float v) {
  return __int_as_float(__builtin_amdgcn_update_dpp(
      ZERO ? 0 : __float_as_int(v), __float_as_int(v), CTRL, 0xF, 0xF, ZERO));
}
// quad_perm xor1=0xB1, xor2=0x4E; row_half_mirror(xor7)=0x141
// row_shr n=0x110+n; bcast15=0x142; bcast31=0x143
__device__ __forceinline__ float rdl63(float v) {
  return __int_as_float(__builtin_amdgcn_readlane(__float_as_int(v), 63));
}
// 8-lane-group reductions (XOR-butterfly masks {1,2,7} span 0..7)
__device__ __forceinline__ float gsum8(float v) {
  v += fdpp<0xB1, true>(v);
  v += fdpp<0x4E, true>(v);
  v += fdpp<0x141, true>(v);
  return v;
}
__device__ __forceinline__ float gmax8(float v) {
  v = fmaxf(v, fdpp<0xB1, false>(v));
  v = fmaxf(v, fdpp<0x4E, false>(v));
  v = fmaxf(v, fdpp<0x141, false>(v));
  return v;
}
__device__ __forceinline__ float wsum_dpp(float v) {
  v += fdpp<0x111, true>(v);
  v += fdpp<0x112, true>(v);
  v += fdpp<0x114, true>(v);
  v += fdpp<0x118, true>(v);
  v += fdpp<0x142, true>(v);
  v += fdpp<0x143, true>(v);
  return rdl63(v);
}
__device__ __forceinline__ float wmax_dpp(float v) {
  v = fmaxf(v, fdpp<0x111, false>(v));
  v = fmaxf(v, fdpp<0x112, false>(v));
  v = fmaxf(v, fdpp<0x114, false>(v));
  v = fmaxf(v, fdpp<0x118, false>(v));
  v = fmaxf(v, fdpp<0x142, false>(v));
  v = fmaxf(v, fdpp<0x143, false>(v));
  return rdl63(v);
}
__device__ __forceinline__ float wmin_dpp(float v) {
  v = fminf(v, fdpp<0x111, false>(v));
  v = fminf(v, fdpp<0x112, false>(v));
  v = fminf(v, fdpp<0x114, false>(v));
  v = fminf(v, fdpp<0x118, false>(v));
  v = fminf(v, fdpp<0x142, false>(v));
  v = fminf(v, fdpp<0x143, false>(v));
  return rdl63(v);
}

__device__ __forceinline__ float wsum64(float v) {  // stages 2/3
#pragma unroll
  for (int m = 1; m <= 32; m <<= 1) v += __shfl_xor(v, m);
  return v;
}

// Non-temporal float4 load (native clang vector type — builtin requires it).
__device__ __forceinline__ floatx4 ntload4(const float* p) {
  return __builtin_nontemporal_load((const floatx4*)p);
}

// ---------------- Kernel A: softmax + head-average, all-sequential DRAM -----
// One block per (b,t): reads its contiguous 128-KB slab (nt), writes P-bar to
// pst[b,t,n,j] -- contiguous 16 KB per block (NO scatter to DRAM).
// 8-lane groups own one n-row across all h; head-avg in registers.
// No LDS, no barriers; 8 blocks/CU -> full 32 waves/CU.
__global__ __launch_bounds__(256, 8) void softmax_kernel(
    const float* __restrict__ sat, float* __restrict__ pst) {
  const int bid = blockIdx.x;      // b*256 + t
  const int tid = threadIdx.x;
  const int sl = tid & 7;          // sub-lane in 8-lane group
  const int grp = tid >> 3;        // group 0..31

  const float* base = sat + (size_t)bid * 32768;  // [h][n][j]
  float* outb = pst + (size_t)bid * 4096;         // [n][j]

#pragma unroll 1
  for (int half = 0; half < 2; ++half) {
    const int n = grp + half * 32;
    const float* rowb = base + n * 64 + sl * 4;

    float acc[8];
#pragma unroll
    for (int c = 0; c < 8; ++c) acc[c] = 0.f;

#pragma unroll 4
    for (int h = 0; h < 8; ++h) {
      const float* p = rowb + h * 4096;
      floatx4 r0 = ntload4(p);
      floatx4 r1 = ntload4(p + 32);
      float m = fmaxf(fmaxf(fmaxf(r0.x, r0.y), fmaxf(r0.z, r0.w)),
                      fmaxf(fmaxf(r1.x, r1.y), fmaxf(r1.z, r1.w)));
      m = gmax8(m);
      float e0 = __expf(r0.x - m), e1 = __expf(r0.y - m);
      float e2 = __expf(r0.z - m), e3 = __expf(r0.w - m);
      float e4 = __expf(r1.x - m), e5 = __expf(r1.y - m);
      float e6 = __expf(r1.z - m), e7 = __expf(r1.w - m);
      float s = gsum8(((e0 + e1) + (e2 + e3)) + ((e4 + e5) + (e6 + e7)));
      float inv = 1.0f / s;
      acc[0] += e0 * inv; acc[1] += e1 * inv;
      acc[2] += e2 * inv; acc[3] += e3 * inv;
      acc[4] += e4 * inv; acc[5] += e5 * inv;
      acc[6] += e6 * inv; acc[7] += e7 * inv;
    }

#pragma unroll
    for (int c = 0; c < 8; ++c) acc[c] *= 0.125f;
    // regular (temporal) stores: pst must stay LLC-resident for kernel B
    *(float4*)(outb + n * 64 + sl * 4) = *(float4*)&acc[0];
    *(float4*)(outb + n * 64 + sl * 4 + 32) = *(float4*)&acc[4];
  }
}

// ---------------- Kernel B: per-(bs,n) stats; l-gather hits LLC -------------
__global__ __launch_bounds__(256, 4) void stats_kernel(
    const float* __restrict__ pst, float* __restrict__ node,
    float* __restrict__ edge, float* __restrict__ score) {
  const int bid = blockIdx.x;  // bs*64 + n
  const int n = bid & 63;
  const int bs = bid >> 6;
  const int tbase = bs * 64;

  __shared__ float Ps[64][64];
  __shared__ float ent_s[64];
  __shared__ float diff_s[64];
  __shared__ float psum_s[4][64];
  __shared__ float dsq_s[4][64];

  const int tid = threadIdx.x;
  const int wave = tid >> 6;
  const int lane = tid & 63;

  // gathered tile load: Ps[l][j] = pst[((tbase+l)*64 + n)*64 + j]
  // 256-B pieces at 16-KB stride -- LLC-resident (67 MB), not DRAM.
#pragma unroll
  for (int i = 0; i < 4; ++i) {
    const int idx = i * 256 + tid;  // 0..1023 float4 slots
    const int row = idx >> 4;
    const int c4 = idx & 15;
    *(float4*)&Ps[row][c4 * 4] =
        *(const float4*)(pst + ((size_t)(tbase + row) * 64 + n) * 64 + c4 * 4);
  }
  __syncthreads();

  // per-l entropy + per-j partials + TV row sums
  {
    const int base = wave * 16;
    float psum = 0.f, dsq = 0.f;
    float p = Ps[base][lane];
#pragma unroll 1
    for (int i = 0; i < 16; ++i) {
      const int ll = base + i;
      float pc = fmaxf(p, EPSV);
      float e = pc * __logf(pc);
      e += fdpp<0x111, true>(e);
      e += fdpp<0x112, true>(e);
      e += fdpp<0x114, true>(e);
      e += fdpp<0x118, true>(e);
      e += fdpp<0x142, true>(e);
      e += fdpp<0x143, true>(e);
      if (lane == 63) ent_s[ll] = -e;
      psum += p;
      if (ll < 63) {
        float pn = Ps[ll + 1][lane];
        float d = pn - p;
        dsq += d * d;
        float ad = fabsf(d);
        ad += fdpp<0x111, true>(ad);
        ad += fdpp<0x112, true>(ad);
        ad += fdpp<0x114, true>(ad);
        ad += fdpp<0x118, true>(ad);
        ad += fdpp<0x142, true>(ad);
        ad += fdpp<0x143, true>(ad);
        if (lane == 63) diff_s[ll] = ad;
        p = pn;
      }
    }
    psum_s[wave][lane] = psum;
    dsq_s[wave][lane] = dsq;
  }
  __syncthreads();

  // edge features (wave 1)
  if (wave == 1) {
    const int j = lane;
    float tot = psum_s[0][j] + psum_s[1][j] + psum_s[2][j] + psum_s[3][j];
    float dsq = dsq_s[0][j] + dsq_s[1][j] + dsq_s[2][j] + dsq_s[3][j];
    float pem = tot * (1.0f / 64.0f);
    float dmean = (Ps[63][j] - Ps[0][j]) * (1.0f / 63.0f);
    float dvar = (dsq - 63.0f * dmean * dmean) * (1.0f / 62.0f);
    float dstd = sqrtf(fmaxf(dvar, 0.f));
    size_t eo = (size_t)bs * 4096 + (size_t)n * 64 + j;
    float4 ef = make_float4(pem, dstd, fmaxf(dmean, 0.f), fmaxf(-dmean, 0.f));
    *(float4*)(edge + eo * 4) = ef;
    score[eo] = (j == n) ? 0.f : fabsf(dmean);
  }

  // node features (wave 0), two-pass variance
  if (wave == 0) {
    float e = ent_s[lane];
    float dg = Ps[lane][n];
    bool dv = lane < 63;
    float df = dv ? diff_s[lane] : 0.f;

    float emean = wsum_dpp(e) * (1.0f / 64.0f);
    float emax = wmax_dpp(e);
    float emin = wmin_dpp(e);
    float dgmean = wsum_dpp(dg) * (1.0f / 64.0f);
    float dfmean = wsum_dpp(df) * (1.0f / 63.0f);
    float dfmax = wmax_dpp(dv ? df : -INFINITY);

    float ed = e - emean;
    float evar = wsum_dpp(ed * ed) * (1.0f / 63.0f);
    float dgd = dg - dgmean;
    float dgvar = wsum_dpp(dgd * dgd) * (1.0f / 63.0f);
    float dfd = dv ? (df - dfmean) : 0.f;
    float dfvar = wsum_dpp(dfd * dfd) * (1.0f / 62.0f);

    if (lane == 0) {
      float* no = node + ((size_t)bs * 64 + n) * 9;
      no[0] = emean;
      no[1] = sqrtf(fmaxf(evar, 0.f));
      no[2] = emax - emin;
      no[3] = (ent_s[63] - ent_s[0]) * (1.0f / 63.0f);
      no[4] = dfmean;
      no[5] = sqrtf(fmaxf(dfvar, 0.f));
      no[6] = dfmax;
      no[7] = dgmean;
      no[8] = sqrtf(fmaxf(dgvar, 0.f));
    }
  }
}

// One workgroup per (b, s): top-16 extraction + feat assembly.
__global__ __launch_bounds__(256) void stage2_kernel(
    const float* __restrict__ node, const float* __restrict__ edge,
    const float* __restrict__ score, float* __restrict__ feat) {
  const int bsid = blockIdx.x;  // b*4+s
  const int b = bsid >> 2, s = bsid & 3;
  __shared__ float sc[4096];
  __shared__ int widx[16];
  __shared__ float rv[4];
  __shared__ int ri[4];
  const int tid = threadIdx.x;
  const int wave = tid >> 6, lane = tid & 63;

  const float* scg = score + (size_t)bsid * 4096;
  for (int i = tid; i < 4096; i += 256) sc[i] = scg[i];
  __syncthreads();

  for (int k = 0; k < 16; ++k) {
    float bv = -1.f;
    int bi = 1 << 30;
    for (int i = tid; i < 4096; i += 256) {
      float v = sc[i];
      if (v > bv) { bv = v; bi = i; }
    }
#pragma unroll
    for (int mk = 1; mk <= 32; mk <<= 1) {
      float ov = __shfl_xor(bv, mk);
      int oi = __shfl_xor(bi, mk);
      if (ov > bv || (ov == bv && oi < bi)) { bv = ov; bi = oi; }
    }
    if (lane == 0) { rv[wave] = bv; ri[wave] = bi; }
    __syncthreads();
    if (tid == 0) {
      float fv = rv[0]; int fi = ri[0];
#pragma unroll
      for (int w = 1; w < 4; ++w)
        if (rv[w] > fv || (rv[w] == fv && ri[w] < fi)) { fv = rv[w]; fi = ri[w]; }
      widx[k] = fi;
      sc[fi] = -1.f;
    }
    __syncthreads();
  }

  float* fout = feat + (size_t)b * 2560 + s * 640;
  const float* nodeg = node + (size_t)bsid * 576;
  for (int i = tid; i < 576; i += 256) fout[i] = nodeg[i];
  if (tid < 16) {
    int idx = widx[tid];
    float4 ef = *(const float4*)(edge + ((size_t)bsid * 4096 + idx) * 4);
    *(float4*)(fout + 576 + tid * 4) = ef;
  }
}

// One workgroup per b: LayerNorm + MLP.
__global__ __launch_bounds__(256) void stage3_kernel(
    const float* __restrict__ feat, const float* __restrict__ gamma,
    const float* __restrict__ beta, const float* __restrict__ W1,
    const float* __restrict__ b1, const float* __restrict__ W2,
    const float* __restrict__ b2, float* __restrict__ out) {
  const int b = blockIdx.x;
  __shared__ float hf[2560];
  __shared__ float rs[4], rq[4];
  __shared__ float part[2][128];
  __shared__ float h1[128];
  __shared__ float part2[4][64];
  const int tid = threadIdx.x;
  const int wave = tid >> 6, lane = tid & 63;

  const float* f = feat + (size_t)b * 2560;
  float lsum = 0.f, lsq = 0.f;
  for (int i = tid; i < 2560; i += 256) {
    float v = f[i];
    hf[i] = v;
    lsum += v;
    lsq += v * v;
  }
  lsum = wsum64(lsum);
  lsq = wsum64(lsq);
  if (lane == 0) { rs[wave] = lsum; rq[wave] = lsq; }
  __syncthreads();
  float tsum = rs[0] + rs[1] + rs[2] + rs[3];
  float tsq = rq[0] + rq[1] + rq[2] + rq[3];
  float mean = tsum * (1.0f / 2560.0f);
  float var = tsq * (1.0f / 2560.0f) - mean * mean;
  float inv = rsqrtf(var + 1e-5f);
  for (int i = tid; i < 2560; i += 256)
    hf[i] = (hf[i] - mean) * inv * gamma[i] + beta[i];
  __syncthreads();

  {
    const int o = tid & 127, half = tid >> 7;
    float acc = 0.f;
    const int i0 = half * 1280;
    for (int i = i0; i < i0 + 1280; ++i) acc += hf[i] * W1[(size_t)i * 128 + o];
    part[half][o] = acc;
  }
  __syncthreads();
  if (tid < 128) h1[tid] = fmaxf(part[0][tid] + part[1][tid] + b1[tid], 0.f);
  __syncthreads();
  {
    const int o = tid & 63, pp = tid >> 6;
    float acc = 0.f;
    const int i0 = pp * 32;
    for (int i = i0; i < i0 + 32; ++i) acc += h1[i] * W2[i * 64 + o];
    part2[pp][o] = acc;
  }
  __syncthreads();
  if (tid < 64)
    out[(size_t)b * 64 + tid] =
        fmaxf(part2[0][tid] + part2[1][tid] + part2[2][tid] + part2[3][tid] + b2[tid], 0.f);
}

extern "C" void kernel_launch(void* const* d_in, const int* in_sizes, int n_in,
                              void* d_out, int out_size, void* d_ws, size_t ws_size,
                              hipStream_t stream) {
  const float* sat = (const float*)d_in[0];
  const float* gamma = (const float*)d_in[1];
  const float* beta = (const float*)d_in[2];
  const float* W1 = (const float*)d_in[3];
  const float* b1 = (const float*)d_in[4];
  const float* W2 = (const float*)d_in[5];
  const float* b2 = (const float*)d_in[6];
  float* out = (float*)d_out;

  float* ws = (float*)d_ws;
  float* pst = ws;                            // 16*4*64*64*64 = 16,777,216 floats
  float* edge = pst + 16777216;               // 1,048,576 floats
  float* score = edge + 16 * 4 * 4096 * 4;    // 262,144 floats
  float* node = score + 16 * 4 * 4096;        // 36,864 floats
  float* feat = node + 16 * 4 * 64 * 9;       // 40,960 floats

  softmax_kernel<<<4096, 256, 0, stream>>>(sat, pst);
  stats_kernel<<<4096, 256, 0, stream>>>(pst, node, edge, score);
  stage2_kernel<<<64, 256, 0, stream>>>(node, edge, score, feat);
  stage3_kernel<<<16, 256, 0, stream>>>(feat, gamma, beta, W1, b1, W2, b2, out);
}

// Round 12
// 180.686 us; speedup vs baseline: 1.4397x; 1.1219x over previous
//
#include <hip/hip_runtime.h>
#include <hip/hip_bf16.h>
#include <math.h>

#define EPSV 1e-8f

typedef float floatx4 __attribute__((ext_vector_type(4)));

// ---------- DPP helpers (VALU-only cross-lane, no LDS pipe) ----------
template <int CTRL, bool ZERO>
__device__ __forceinline__ float fdpp(float v) {
  return __int_as_float(__builtin_amdgcn_update_dpp(
      ZERO ? 0 : __float_as_int(v), __float_as_int(v), CTRL, 0xF, 0xF, ZERO));
}
// quad_perm xor1=0xB1, xor2=0x4E; row_half_mirror(xor7)=0x141
// row_shr n=0x110+n; bcast15=0x142; bcast31=0x143
__device__ __forceinline__ float rdl63(float v) {
  return __int_as_float(__builtin_amdgcn_readlane(__float_as_int(v), 63));
}
// 8-lane-group reductions (XOR-butterfly masks {1,2,7} span 0..7)
__device__ __forceinline__ float gsum8(float v) {
  v += fdpp<0xB1, true>(v);
  v += fdpp<0x4E, true>(v);
  v += fdpp<0x141, true>(v);
  return v;
}
__device__ __forceinline__ float gmax8(float v) {
  v = fmaxf(v, fdpp<0xB1, false>(v));
  v = fmaxf(v, fdpp<0x4E, false>(v));
  v = fmaxf(v, fdpp<0x141, false>(v));
  return v;
}
__device__ __forceinline__ float wsum_dpp(float v) {
  v += fdpp<0x111, true>(v);
  v += fdpp<0x112, true>(v);
  v += fdpp<0x114, true>(v);
  v += fdpp<0x118, true>(v);
  v += fdpp<0x142, true>(v);
  v += fdpp<0x143, true>(v);
  return rdl63(v);
}
__device__ __forceinline__ float wmax_dpp(float v) {
  v = fmaxf(v, fdpp<0x111, false>(v));
  v = fmaxf(v, fdpp<0x112, false>(v));
  v = fmaxf(v, fdpp<0x114, false>(v));
  v = fmaxf(v, fdpp<0x118, false>(v));
  v = fmaxf(v, fdpp<0x142, false>(v));
  v = fmaxf(v, fdpp<0x143, false>(v));
  return rdl63(v);
}
__device__ __forceinline__ float wmin_dpp(float v) {
  v = fminf(v, fdpp<0x111, false>(v));
  v = fminf(v, fdpp<0x112, false>(v));
  v = fminf(v, fdpp<0x114, false>(v));
  v = fminf(v, fdpp<0x118, false>(v));
  v = fminf(v, fdpp<0x142, false>(v));
  v = fminf(v, fdpp<0x143, false>(v));
  return rdl63(v);
}

__device__ __forceinline__ float wsum64(float v) {  // stages 2/3
#pragma unroll
  for (int m = 1; m <= 32; m <<= 1) v += __shfl_xor(v, m);
  return v;
}

// One workgroup per (b, s, n): 4096 blocks x 512 threads (8 waves).
// Phase 1: 3-slab LDS ring, DMA-staged via global_load_lds (NT), counted
// vmcnt — no barriers in the h-loop (each wave stages & consumes only its
// own 8 rows). Registers stay ~40 -> occupancy LDS-bound at 3 blocks/CU
// (24 waves/CU), in-flight bytes ~2x the direct-load version.
__global__ __launch_bounds__(512, 6) void stage1_kernel(
    const float* __restrict__ sat, float* __restrict__ node,
    float* __restrict__ edge, float* __restrict__ score) {
  const int bid = blockIdx.x;
  const int n = bid & 63;
  const int bs = bid >> 6;
  const int tbase = bs * 64;

  __shared__ float buf[3][64][64];   // 48 KB staging ring; buf[0] reused as Ps
  __shared__ float ent_s[64];
  __shared__ float diff_s[64];
  __shared__ float psum_s[8][64];
  __shared__ float dsq_s[8][64];
  float (*Ps)[64] = buf[0];

  const int tid = threadIdx.x;
  const int wave = tid >> 6;   // 0..7
  const int lane = tid & 63;
  const int grp_l = tid >> 3;  // row 0..63 owned by this 8-lane group
  const int sl = tid & 7;      // sub-lane in row
  const int w8 = wave * 8;

  // wave-base global pointer: rows tbase+w8.., head 0, col 0 of column n
  const float* sat_w = sat + (size_t)(tbase + w8) * 32768 + n * 64;

  // stage slab h into buf[h%3][w8..w8+7][:]  (2 x 1-KB DMA instructions)
  auto stage = [&](int h) {
    const int d = h % 3;
    const float* g0 =
        sat_w + (size_t)h * 4096 + (size_t)(lane >> 4) * 32768 + (lane & 15) * 4;
    __builtin_amdgcn_global_load_lds(
        (const __attribute__((address_space(1))) void*)g0,
        (__attribute__((address_space(3))) void*)&buf[d][w8][0], 16, 0, 2);
    const float* g1 = g0 + 4ull * 32768;
    __builtin_amdgcn_global_load_lds(
        (const __attribute__((address_space(1))) void*)g1,
        (__attribute__((address_space(3))) void*)&buf[d][w8 + 4][0], 16, 0, 2);
  };

  // ---- phase 1: softmax over j (64), mean over h (8) -> Ps[l][j] ----
  stage(0);
  stage(1);
  stage(2);

  float acc[8];
#pragma unroll
  for (int c = 0; c < 8; ++c) acc[c] = 0.f;

#pragma unroll
  for (int h = 0; h < 8; ++h) {
    // slab h ready when outstanding <= 2*(slabs_in_flight - 1)
    if (h <= 5) {
      asm volatile("s_waitcnt vmcnt(4)" ::: "memory");
    } else if (h == 6) {
      asm volatile("s_waitcnt vmcnt(2)" ::: "memory");
    } else {
      asm volatile("s_waitcnt vmcnt(0)" ::: "memory");
    }
    __builtin_amdgcn_sched_barrier(0);

    float4 r0 = *(const float4*)&buf[h % 3][grp_l][sl * 4];
    float4 r1 = *(const float4*)&buf[h % 3][grp_l][sl * 4 + 32];

    float m = fmaxf(fmaxf(fmaxf(r0.x, r0.y), fmaxf(r0.z, r0.w)),
                    fmaxf(fmaxf(r1.x, r1.y), fmaxf(r1.z, r1.w)));
    m = gmax8(m);
    float e0 = __expf(r0.x - m), e1 = __expf(r0.y - m);
    float e2 = __expf(r0.z - m), e3 = __expf(r0.w - m);
    float e4 = __expf(r1.x - m), e5 = __expf(r1.y - m);
    float e6 = __expf(r1.z - m), e7 = __expf(r1.w - m);
    float s = gsum8(((e0 + e1) + (e2 + e3)) + ((e4 + e5) + (e6 + e7)));
    float inv = 1.0f / s;
    acc[0] += e0 * inv; acc[1] += e1 * inv;
    acc[2] += e2 * inv; acc[3] += e3 * inv;
    acc[4] += e4 * inv; acc[5] += e5 * inv;
    acc[6] += e6 * inv; acc[7] += e7 * inv;

    if (h + 3 < 8) stage(h + 3);  // refill ring (same buffer just consumed)
  }

  // entropy in-register (head-avg applied first)
  float ent = 0.f;
#pragma unroll
  for (int c = 0; c < 8; ++c) {
    acc[c] *= 0.125f;
    float pc = fmaxf(acc[c], EPSV);
    ent += pc * __logf(pc);
  }
  ent = gsum8(ent);
  if (sl == 0) ent_s[grp_l] = -ent;

  // Ps overlays buf[0]: this wave consumed its buf[0] rows (h=6) already,
  // and no other wave touches these rows.
  *(float4*)&Ps[grp_l][sl * 4] = *(float4*)&acc[0];
  *(float4*)&Ps[grp_l][sl * 4 + 32] = *(float4*)&acc[4];
  __syncthreads();

  // ---- phase 2a: per-j partials over this wave's 8 rows + TV row sums ----
  {
    const int base = wave * 8;
    float psum = 0.f, dsq = 0.f;
    float p = Ps[base][lane];
#pragma unroll 1
    for (int i = 0; i < 8; ++i) {
      const int ll = base + i;
      psum += p;
      if (ll < 63) {
        float pn = Ps[ll + 1][lane];
        float d = pn - p;
        dsq += d * d;
        float ad = fabsf(d);
        ad += fdpp<0x111, true>(ad);
        ad += fdpp<0x112, true>(ad);
        ad += fdpp<0x114, true>(ad);
        ad += fdpp<0x118, true>(ad);
        ad += fdpp<0x142, true>(ad);
        ad += fdpp<0x143, true>(ad);
        if (lane == 63) diff_s[ll] = ad;
        p = pn;
      }
    }
    psum_s[wave][lane] = psum;
    dsq_s[wave][lane] = dsq;
  }
  __syncthreads();

  // ---- phase 2c: edge features (wave 1) ----
  if (wave == 1) {
    const int j = lane;
    float tot = 0.f, dsq = 0.f;
#pragma unroll
    for (int w = 0; w < 8; ++w) {
      tot += psum_s[w][j];
      dsq += dsq_s[w][j];
    }
    float pem = tot * (1.0f / 64.0f);
    float dmean = (Ps[63][j] - Ps[0][j]) * (1.0f / 63.0f);
    float dvar = (dsq - 63.0f * dmean * dmean) * (1.0f / 62.0f);
    float dstd = sqrtf(fmaxf(dvar, 0.f));
    size_t eo = (size_t)bs * 4096 + (size_t)n * 64 + j;
    float4 ef = make_float4(pem, dstd, fmaxf(dmean, 0.f), fmaxf(-dmean, 0.f));
    *(float4*)(edge + eo * 4) = ef;
    score[eo] = (j == n) ? 0.f : fabsf(dmean);
  }

  // ---- phase 2d: node features (wave 0), two-pass variance, DPP ----
  if (wave == 0) {
    float e = ent_s[lane];
    float dg = Ps[lane][n];
    bool dv = lane < 63;
    float df = dv ? diff_s[lane] : 0.f;

    float emean = wsum_dpp(e) * (1.0f / 64.0f);
    float emax = wmax_dpp(e);
    float emin = wmin_dpp(e);
    float dgmean = wsum_dpp(dg) * (1.0f / 64.0f);
    float dfmean = wsum_dpp(df) * (1.0f / 63.0f);
    float dfmax = wmax_dpp(dv ? df : -INFINITY);

    float ed = e - emean;
    float evar = wsum_dpp(ed * ed) * (1.0f / 63.0f);
    float dgd = dg - dgmean;
    float dgvar = wsum_dpp(dgd * dgd) * (1.0f / 63.0f);
    float dfd = dv ? (df - dfmean) : 0.f;
    float dfvar = wsum_dpp(dfd * dfd) * (1.0f / 62.0f);

    if (lane == 0) {
      float* no = node + ((size_t)bs * 64 + n) * 9;
      no[0] = emean;
      no[1] = sqrtf(fmaxf(evar, 0.f));
      no[2] = emax - emin;
      no[3] = (ent_s[63] - ent_s[0]) * (1.0f / 63.0f);
      no[4] = dfmean;
      no[5] = sqrtf(fmaxf(dfvar, 0.f));
      no[6] = dfmax;
      no[7] = dgmean;
      no[8] = sqrtf(fmaxf(dgvar, 0.f));
    }
  }
}

// One workgroup per (b, s): top-16 extraction + feat assembly.
__global__ __launch_bounds__(256) void stage2_kernel(
    const float* __restrict__ node, const float* __restrict__ edge,
    const float* __restrict__ score, float* __restrict__ feat) {
  const int bsid = blockIdx.x;  // b*4+s
  const int b = bsid >> 2, s = bsid & 3;
  __shared__ float sc[4096];
  __shared__ int widx[16];
  __shared__ float rv[4];
  __shared__ int ri[4];
  const int tid = threadIdx.x;
  const int wave = tid >> 6, lane = tid & 63;

  const float* scg = score + (size_t)bsid * 4096;
  for (int i = tid; i < 4096; i += 256) sc[i] = scg[i];
  __syncthreads();

  for (int k = 0; k < 16; ++k) {
    float bv = -1.f;
    int bi = 1 << 30;
    for (int i = tid; i < 4096; i += 256) {
      float v = sc[i];
      if (v > bv) { bv = v; bi = i; }
    }
#pragma unroll
    for (int mk = 1; mk <= 32; mk <<= 1) {
      float ov = __shfl_xor(bv, mk);
      int oi = __shfl_xor(bi, mk);
      if (ov > bv || (ov == bv && oi < bi)) { bv = ov; bi = oi; }
    }
    if (lane == 0) { rv[wave] = bv; ri[wave] = bi; }
    __syncthreads();
    if (tid == 0) {
      float fv = rv[0]; int fi = ri[0];
#pragma unroll
      for (int w = 1; w < 4; ++w)
        if (rv[w] > fv || (rv[w] == fv && ri[w] < fi)) { fv = rv[w]; fi = ri[w]; }
      widx[k] = fi;
      sc[fi] = -1.f;
    }
    __syncthreads();
  }

  float* fout = feat + (size_t)b * 2560 + s * 640;
  const float* nodeg = node + (size_t)bsid * 576;
  for (int i = tid; i < 576; i += 256) fout[i] = nodeg[i];
  if (tid < 16) {
    int idx = widx[tid];
    float4 ef = *(const float4*)(edge + ((size_t)bsid * 4096 + idx) * 4);
    *(float4*)(fout + 576 + tid * 4) = ef;
  }
}

// One workgroup per b: LayerNorm + MLP.
__global__ __launch_bounds__(256) void stage3_kernel(
    const float* __restrict__ feat, const float* __restrict__ gamma,
    const float* __restrict__ beta, const float* __restrict__ W1,
    const float* __restrict__ b1, const float* __restrict__ W2,
    const float* __restrict__ b2, float* __restrict__ out) {
  const int b = blockIdx.x;
  __shared__ float hf[2560];
  __shared__ float rs[4], rq[4];
  __shared__ float part[2][128];
  __shared__ float h1[128];
  __shared__ float part2[4][64];
  const int tid = threadIdx.x;
  const int wave = tid >> 6, lane = tid & 63;

  const float* f = feat + (size_t)b * 2560;
  float lsum = 0.f, lsq = 0.f;
  for (int i = tid; i < 2560; i += 256) {
    float v = f[i];
    hf[i] = v;
    lsum += v;
    lsq += v * v;
  }
  lsum = wsum64(lsum);
  lsq = wsum64(lsq);
  if (lane == 0) { rs[wave] = lsum; rq[wave] = lsq; }
  __syncthreads();
  float tsum = rs[0] + rs[1] + rs[2] + rs[3];
  float tsq = rq[0] + rq[1] + rq[2] + rq[3];
  float mean = tsum * (1.0f / 2560.0f);
  float var = tsq * (1.0f / 2560.0f) - mean * mean;
  float inv = rsqrtf(var + 1e-5f);
  for (int i = tid; i < 2560; i += 256)
    hf[i] = (hf[i] - mean) * inv * gamma[i] + beta[i];
  __syncthreads();

  {
    const int o = tid & 127, half = tid >> 7;
    float acc = 0.f;
    const int i0 = half * 1280;
    for (int i = i0; i < i0 + 1280; ++i) acc += hf[i] * W1[(size_t)i * 128 + o];
    part[half][o] = acc;
  }
  __syncthreads();
  if (tid < 128) h1[tid] = fmaxf(part[0][tid] + part[1][tid] + b1[tid], 0.f);
  __syncthreads();
  {
    const int o = tid & 63, pp = tid >> 6;
    float acc = 0.f;
    const int i0 = pp * 32;
    for (int i = i0; i < i0 + 32; ++i) acc += h1[i] * W2[i * 64 + o];
    part2[pp][o] = acc;
  }
  __syncthreads();
  if (tid < 64)
    out[(size_t)b * 64 + tid] =
        fmaxf(part2[0][tid] + part2[1][tid] + part2[2][tid] + part2[3][tid] + b2[tid], 0.f);
}

extern "C" void kernel_launch(void* const* d_in, const int* in_sizes, int n_in,
                              void* d_out, int out_size, void* d_ws, size_t ws_size,
                              hipStream_t stream) {
  const float* sat = (const float*)d_in[0];
  const float* gamma = (const float*)d_in[1];
  const float* beta = (const float*)d_in[2];
  const float* W1 = (const float*)d_in[3];
  const float* b1 = (const float*)d_in[4];
  const float* W2 = (const float*)d_in[5];
  const float* b2 = (const float*)d_in[6];
  float* out = (float*)d_out;

  float* ws = (float*)d_ws;
  float* edge = ws;                          // 16*4*4096*4 floats
  float* score = edge + 16 * 4 * 4096 * 4;   // 262144 floats
  float* node = score + 16 * 4 * 4096;       // 36864 floats
  float* feat = node + 16 * 4 * 64 * 9;      // 40960 floats

  stage1_kernel<<<4096, 512, 0, stream>>>(sat, node, edge, score);
  stage2_kernel<<<64, 256, 0, stream>>>(node, edge, score, feat);
  stage3_kernel<<<16, 256, 0, stream>>>(feat, gamma, beta, W1, b1, W2, b2, out);
}

// Round 13
// 150.994 us; speedup vs baseline: 1.7228x; 1.1966x over previous
//
#include <hip/hip_runtime.h>
#include <hip/hip_bf16.h>
#include <math.h>

#define EPSV 1e-8f

typedef float floatx4 __attribute__((ext_vector_type(4)));

// ---------- DPP helpers (VALU-only cross-lane, no LDS pipe) ----------
template <int CTRL, bool ZERO>
__device__ __forceinline__ float fdpp(float v) {
  return __int_as_float(__builtin_amdgcn_update_dpp(
      ZERO ? 0 : __float_as_int(v), __float_as_int(v), CTRL, 0xF, 0xF, ZERO));
}
// quad_perm xor1=0xB1, xor2=0x4E; row_half_mirror(xor7)=0x141
// row_shr n=0x110+n; bcast15=0x142; bcast31=0x143
__device__ __forceinline__ float rdl63(float v) {
  return __int_as_float(__builtin_amdgcn_readlane(__float_as_int(v), 63));
}
// 8-lane-group reductions (XOR-butterfly masks {1,2,7} span 0..7)
__device__ __forceinline__ float gsum8(float v) {
  v += fdpp<0xB1, true>(v);
  v += fdpp<0x4E, true>(v);
  v += fdpp<0x141, true>(v);
  return v;
}
__device__ __forceinline__ float gmax8(float v) {
  v = fmaxf(v, fdpp<0xB1, false>(v));
  v = fmaxf(v, fdpp<0x4E, false>(v));
  v = fmaxf(v, fdpp<0x141, false>(v));
  return v;
}
__device__ __forceinline__ float wsum_dpp(float v) {
  v += fdpp<0x111, true>(v);
  v += fdpp<0x112, true>(v);
  v += fdpp<0x114, true>(v);
  v += fdpp<0x118, true>(v);
  v += fdpp<0x142, true>(v);
  v += fdpp<0x143, true>(v);
  return rdl63(v);
}
__device__ __forceinline__ float wmax_dpp(float v) {
  v = fmaxf(v, fdpp<0x111, false>(v));
  v = fmaxf(v, fdpp<0x112, false>(v));
  v = fmaxf(v, fdpp<0x114, false>(v));
  v = fmaxf(v, fdpp<0x118, false>(v));
  v = fmaxf(v, fdpp<0x142, false>(v));
  v = fmaxf(v, fdpp<0x143, false>(v));
  return rdl63(v);
}
__device__ __forceinline__ float wmin_dpp(float v) {
  v = fminf(v, fdpp<0x111, false>(v));
  v = fminf(v, fdpp<0x112, false>(v));
  v = fminf(v, fdpp<0x114, false>(v));
  v = fminf(v, fdpp<0x118, false>(v));
  v = fminf(v, fdpp<0x142, false>(v));
  v = fminf(v, fdpp<0x143, false>(v));
  return rdl63(v);
}

__device__ __forceinline__ float wsum64(float v) {  // stages 2/3
#pragma unroll
  for (int m = 1; m <= 32; m <<= 1) v += __shfl_xor(v, m);
  return v;
}

// Non-temporal float4 load (native clang vector type — builtin requires it).
__device__ __forceinline__ floatx4 ntload4(const float* p) {
  return __builtin_nontemporal_load((const floatx4*)p);
}

// One workgroup per (b, s, n): 4096 blocks x 512 threads (8 waves).
// 8 lanes per (l) row, each lane owns 8 elements (two float4 loads/h).
// Low VGPR (acc[8]) -> fits 64-reg cap -> 8 waves/SIMD (32 waves/CU) for
// double the memory-level parallelism. Non-temporal loads retained.
__global__ __launch_bounds__(512, 8) void stage1_kernel(
    const float* __restrict__ sat, float* __restrict__ node,
    float* __restrict__ edge, float* __restrict__ score) {
  const int bid = blockIdx.x;
  const int n = bid & 63;
  const int bs = bid >> 6;
  const int tbase = bs * 64;

  __shared__ float Ps[64][64];
  __shared__ float ent_s[64];
  __shared__ float diff_s[64];
  __shared__ float psum_s[8][64];
  __shared__ float dsq_s[8][64];

  const int tid = threadIdx.x;
  const int wave = tid >> 6;   // 0..7
  const int lane = tid & 63;
  const int rsub = lane >> 3;  // row-in-wave 0..7
  const int sl = lane & 7;     // sub-lane in row
  const int l = wave * 8 + rsub;

  // ---- phase 1: softmax over j (64), mean over h (8) -> Ps[l][j] ----
  // lane holds elements j = sl*4..sl*4+3 and sl*4+32..sl*4+35
  const float* rowb =
      sat + (size_t)(tbase + l) * 32768 + n * 64 + sl * 4;

  float acc[8];
#pragma unroll
  for (int c = 0; c < 8; ++c) acc[c] = 0.f;

#pragma unroll 4
  for (int h = 0; h < 8; ++h) {
    const float* p = rowb + h * 4096;
    floatx4 r0 = ntload4(p);
    floatx4 r1 = ntload4(p + 32);
    float m = fmaxf(fmaxf(fmaxf(r0.x, r0.y), fmaxf(r0.z, r0.w)),
                    fmaxf(fmaxf(r1.x, r1.y), fmaxf(r1.z, r1.w)));
    m = gmax8(m);
    float e0 = __expf(r0.x - m), e1 = __expf(r0.y - m);
    float e2 = __expf(r0.z - m), e3 = __expf(r0.w - m);
    float e4 = __expf(r1.x - m), e5 = __expf(r1.y - m);
    float e6 = __expf(r1.z - m), e7 = __expf(r1.w - m);
    float s = gsum8(((e0 + e1) + (e2 + e3)) + ((e4 + e5) + (e6 + e7)));
    float inv = 1.0f / s;
    acc[0] += e0 * inv; acc[1] += e1 * inv;
    acc[2] += e2 * inv; acc[3] += e3 * inv;
    acc[4] += e4 * inv; acc[5] += e5 * inv;
    acc[6] += e6 * inv; acc[7] += e7 * inv;
  }

  // entropy in-register (head-avg applied first)
  float ent = 0.f;
#pragma unroll
  for (int c = 0; c < 8; ++c) {
    acc[c] *= 0.125f;
    float pc = fmaxf(acc[c], EPSV);
    ent += pc * __logf(pc);
  }
  ent = gsum8(ent);
  if (sl == 0) ent_s[l] = -ent;

  *(float4*)&Ps[l][sl * 4] = *(float4*)&acc[0];
  *(float4*)&Ps[l][sl * 4 + 32] = *(float4*)&acc[4];
  __syncthreads();

  // ---- phase 2a: per-j partials over this wave's 8 rows + TV row sums ----
  {
    const int base = wave * 8;
    float psum = 0.f, dsq = 0.f;
    float p = Ps[base][lane];
#pragma unroll 1
    for (int i = 0; i < 8; ++i) {
      const int ll = base + i;
      psum += p;
      if (ll < 63) {
        float pn = Ps[ll + 1][lane];
        float d = pn - p;
        dsq += d * d;
        float ad = fabsf(d);
        ad += fdpp<0x111, true>(ad);
        ad += fdpp<0x112, true>(ad);
        ad += fdpp<0x114, true>(ad);
        ad += fdpp<0x118, true>(ad);
        ad += fdpp<0x142, true>(ad);
        ad += fdpp<0x143, true>(ad);
        if (lane == 63) diff_s[ll] = ad;
        p = pn;
      }
    }
    psum_s[wave][lane] = psum;
    dsq_s[wave][lane] = dsq;
  }
  __syncthreads();

  // ---- phase 2c: edge features (wave 1) ----
  if (wave == 1) {
    const int j = lane;
    float tot = 0.f, dsq = 0.f;
#pragma unroll
    for (int w = 0; w < 8; ++w) {
      tot += psum_s[w][j];
      dsq += dsq_s[w][j];
    }
    float pem = tot * (1.0f / 64.0f);
    float dmean = (Ps[63][j] - Ps[0][j]) * (1.0f / 63.0f);
    float dvar = (dsq - 63.0f * dmean * dmean) * (1.0f / 62.0f);
    float dstd = sqrtf(fmaxf(dvar, 0.f));
    size_t eo = (size_t)bs * 4096 + (size_t)n * 64 + j;
    float4 ef = make_float4(pem, dstd, fmaxf(dmean, 0.f), fmaxf(-dmean, 0.f));
    *(float4*)(edge + eo * 4) = ef;
    score[eo] = (j == n) ? 0.f : fabsf(dmean);
  }

  // ---- phase 2d: node features (wave 0), two-pass variance, DPP ----
  if (wave == 0) {
    float e = ent_s[lane];
    float dg = Ps[lane][n];
    bool dv = lane < 63;
    float df = dv ? diff_s[lane] : 0.f;

    float emean = wsum_dpp(e) * (1.0f / 64.0f);
    float emax = wmax_dpp(e);
    float emin = wmin_dpp(e);
    float dgmean = wsum_dpp(dg) * (1.0f / 64.0f);
    float dfmean = wsum_dpp(df) * (1.0f / 63.0f);
    float dfmax = wmax_dpp(dv ? df : -INFINITY);

    float ed = e - emean;
    float evar = wsum_dpp(ed * ed) * (1.0f / 63.0f);
    float dgd = dg - dgmean;
    float dgvar = wsum_dpp(dgd * dgd) * (1.0f / 63.0f);
    float dfd = dv ? (df - dfmean) : 0.f;
    float dfvar = wsum_dpp(dfd * dfd) * (1.0f / 62.0f);

    if (lane == 0) {
      float* no = node + ((size_t)bs * 64 + n) * 9;
      no[0] = emean;
      no[1] = sqrtf(fmaxf(evar, 0.f));
      no[2] = emax - emin;
      no[3] = (ent_s[63] - ent_s[0]) * (1.0f / 63.0f);
      no[4] = dfmean;
      no[5] = sqrtf(fmaxf(dfvar, 0.f));
      no[6] = dfmax;
      no[7] = dgmean;
      no[8] = sqrtf(fmaxf(dgvar, 0.f));
    }
  }
}

// One workgroup per (b, s): top-16 extraction + feat assembly.
__global__ __launch_bounds__(256) void stage2_kernel(
    const float* __restrict__ node, const float* __restrict__ edge,
    const float* __restrict__ score, float* __restrict__ feat) {
  const int bsid = blockIdx.x;  // b*4+s
  const int b = bsid >> 2, s = bsid & 3;
  __shared__ float sc[4096];
  __shared__ int widx[16];
  __shared__ float rv[4];
  __shared__ int ri[4];
  const int tid = threadIdx.x;
  const int wave = tid >> 6, lane = tid & 63;

  const float* scg = score + (size_t)bsid * 4096;
  for (int i = tid; i < 4096; i += 256) sc[i] = scg[i];
  __syncthreads();

  for (int k = 0; k < 16; ++k) {
    float bv = -1.f;
    int bi = 1 << 30;
    for (int i = tid; i < 4096; i += 256) {
      float v = sc[i];
      if (v > bv) { bv = v; bi = i; }
    }
#pragma unroll
    for (int mk = 1; mk <= 32; mk <<= 1) {
      float ov = __shfl_xor(bv, mk);
      int oi = __shfl_xor(bi, mk);
      if (ov > bv || (ov == bv && oi < bi)) { bv = ov; bi = oi; }
    }
    if (lane == 0) { rv[wave] = bv; ri[wave] = bi; }
    __syncthreads();
    if (tid == 0) {
      float fv = rv[0]; int fi = ri[0];
#pragma unroll
      for (int w = 1; w < 4; ++w)
        if (rv[w] > fv || (rv[w] == fv && ri[w] < fi)) { fv = rv[w]; fi = ri[w]; }
      widx[k] = fi;
      sc[fi] = -1.f;
    }
    __syncthreads();
  }

  float* fout = feat + (size_t)b * 2560 + s * 640;
  const float* nodeg = node + (size_t)bsid * 576;
  for (int i = tid; i < 576; i += 256) fout[i] = nodeg[i];
  if (tid < 16) {
    int idx = widx[tid];
    float4 ef = *(const float4*)(edge + ((size_t)bsid * 4096 + idx) * 4);
    *(float4*)(fout + 576 + tid * 4) = ef;
  }
}

// One workgroup per b: LayerNorm + MLP.
__global__ __launch_bounds__(256) void stage3_kernel(
    const float* __restrict__ feat, const float* __restrict__ gamma,
    const float* __restrict__ beta, const float* __restrict__ W1,
    const float* __restrict__ b1, const float* __restrict__ W2,
    const float* __restrict__ b2, float* __restrict__ out) {
  const int b = blockIdx.x;
  __shared__ float hf[2560];
  __shared__ float rs[4], rq[4];
  __shared__ float part[2][128];
  __shared__ float h1[128];
  __shared__ float part2[4][64];
  const int tid = threadIdx.x;
  const int wave = tid >> 6, lane = tid & 63;

  const float* f = feat + (size_t)b * 2560;
  float lsum = 0.f, lsq = 0.f;
  for (int i = tid; i < 2560; i += 256) {
    float v = f[i];
    hf[i] = v;
    lsum += v;
    lsq += v * v;
  }
  lsum = wsum64(lsum);
  lsq = wsum64(lsq);
  if (lane == 0) { rs[wave] = lsum; rq[wave] = lsq; }
  __syncthreads();
  float tsum = rs[0] + rs[1] + rs[2] + rs[3];
  float tsq = rq[0] + rq[1] + rq[2] + rq[3];
  float mean = tsum * (1.0f / 2560.0f);
  float var = tsq * (1.0f / 2560.0f) - mean * mean;
  float inv = rsqrtf(var + 1e-5f);
  for (int i = tid; i < 2560; i += 256)
    hf[i] = (hf[i] - mean) * inv * gamma[i] + beta[i];
  __syncthreads();

  {
    const int o = tid & 127, half = tid >> 7;
    float acc = 0.f;
    const int i0 = half * 1280;
    for (int i = i0; i < i0 + 1280; ++i) acc += hf[i] * W1[(size_t)i * 128 + o];
    part[half][o] = acc;
  }
  __syncthreads();
  if (tid < 128) h1[tid] = fmaxf(part[0][tid] + part[1][tid] + b1[tid], 0.f);
  __syncthreads();
  {
    const int o = tid & 63, pp = tid >> 6;
    float acc = 0.f;
    const int i0 = pp * 32;
    for (int i = i0; i < i0 + 32; ++i) acc += h1[i] * W2[i * 64 + o];
    part2[pp][o] = acc;
  }
  __syncthreads();
  if (tid < 64)
    out[(size_t)b * 64 + tid] =
        fmaxf(part2[0][tid] + part2[1][tid] + part2[2][tid] + part2[3][tid] + b2[tid], 0.f);
}

extern "C" void kernel_launch(void* const* d_in, const int* in_sizes, int n_in,
                              void* d_out, int out_size, void* d_ws, size_t ws_size,
                              hipStream_t stream) {
  const float* sat = (const float*)d_in[0];
  const float* gamma = (const float*)d_in[1];
  const float* beta = (const float*)d_in[2];
  const float* W1 = (const float*)d_in[3];
  const float* b1 = (const float*)d_in[4];
  const float* W2 = (const float*)d_in[5];
  const float* b2 = (const float*)d_in[6];
  float* out = (float*)d_out;

  float* ws = (float*)d_ws;
  float* edge = ws;                          // 16*4*4096*4 floats
  float* score = edge + 16 * 4 * 4096 * 4;   // 262144 floats
  float* node = score + 16 * 4 * 4096;       // 36864 floats
  float* feat = node + 16 * 4 * 64 * 9;      // 40960 floats

  stage1_kernel<<<4096, 512, 0, stream>>>(sat, node, edge, score);
  stage2_kernel<<<64, 256, 0, stream>>>(node, edge, score, feat);
  stage3_kernel<<<16, 256, 0, stream>>>(feat, gamma, beta, W1, b1, W2, b2, out);
}